// Round 3
// baseline (7151.022 us; speedup 1.0000x reference)
//
#include <hip/hip_runtime.h>

#define IGNORE_INDEX (-100)
#define VOCAB 32000
#define DDIM  2048      /* K in elements; == bytes per row in fp8 */
#define MTOK  8192      /* B*S = 4*2048 */

#define BM 256
#define BN 128
#define BK 128          /* fp8 elems (bytes) per K-tile */
#define NKT (DDIM / BK) /* 16 K-tiles */

#define WSCALE 32.0f
#define HSCALE 8.0f
#define INVSCALE (1.0f / 256.0f)
#define SCALE_ONE 0x7F7F7F7F  /* e8m0 1.0 in every byte */

#define WBLK ((VOCAB * DDIM) / (256 * 16))   /* 16000 */
#define HBLK ((MTOK * DDIM) / (256 * 16))    /*  4096 */
#define ZBLK ((2 * MTOK * 4) / (256 * 16))   /*    16: zero sumexp+tgtlogit */

typedef float f32x4 __attribute__((ext_vector_type(4)));
typedef int   i32x8 __attribute__((ext_vector_type(8)));
typedef unsigned char uchar_t;

// ---------------- fp32 -> fp8 e4m3 (OCP, RNE via HW cvt), 16 elems/thread ----
__device__ __forceinline__ void cvt16(const float4* __restrict__ src,
                                      int4* __restrict__ dst, float scale,
                                      size_t i) {
    float4 a = src[4 * i], b = src[4 * i + 1], c = src[4 * i + 2], d = src[4 * i + 3];
    int4 o;
    int v;
    v = 0;
    v = __builtin_amdgcn_cvt_pk_fp8_f32(a.x * scale, a.y * scale, v, false);
    v = __builtin_amdgcn_cvt_pk_fp8_f32(a.z * scale, a.w * scale, v, true);
    o.x = v;
    v = 0;
    v = __builtin_amdgcn_cvt_pk_fp8_f32(b.x * scale, b.y * scale, v, false);
    v = __builtin_amdgcn_cvt_pk_fp8_f32(b.z * scale, b.w * scale, v, true);
    o.y = v;
    v = 0;
    v = __builtin_amdgcn_cvt_pk_fp8_f32(c.x * scale, c.y * scale, v, false);
    v = __builtin_amdgcn_cvt_pk_fp8_f32(c.z * scale, c.w * scale, v, true);
    o.z = v;
    v = 0;
    v = __builtin_amdgcn_cvt_pk_fp8_f32(d.x * scale, d.y * scale, v, false);
    v = __builtin_amdgcn_cvt_pk_fp8_f32(d.z * scale, d.w * scale, v, true);
    o.w = v;
    dst[i] = o;
}

// Fused: weight cvt | hidden cvt | zero accumulators (ws poisoned each call).
__global__ void cvt_f32_fp8(const float4* __restrict__ srcW, int4* __restrict__ dstW,
                            const float4* __restrict__ srcH, int4* __restrict__ dstH,
                            int4* __restrict__ zr) {
    if (blockIdx.x < WBLK) {
        size_t i = (size_t)blockIdx.x * blockDim.x + threadIdx.x;
        cvt16(srcW, dstW, WSCALE, i);
    } else if (blockIdx.x < WBLK + HBLK) {
        size_t i = (size_t)(blockIdx.x - WBLK) * blockDim.x + threadIdx.x;
        cvt16(srcH, dstH, HSCALE, i);
    } else {
        int i = (blockIdx.x - WBLK - HBLK) * 256 + threadIdx.x;
        zr[i] = make_int4(0, 0, 0, 0);
    }
}

// ---------------- async global -> LDS (16 B per lane) ----------------
__device__ __forceinline__ void load_lds16(const uchar_t* g, uchar_t* l) {
    __builtin_amdgcn_global_load_lds(
        (const __attribute__((address_space(1))) unsigned int*)(const void*)g,
        (__attribute__((address_space(3))) unsigned int*)(void*)l,
        16, 0, 0);
}

// 32 B fragment read with 16B-slot XOR swizzle: logical slots (2q, 2q+1) of a
// row live at physical slots (2q)^(row&7), (2q+1)^(row&7). off already encodes
// row*BK + ((2q)^(row&7))<<4; the odd slot is off^16 (XOR flips only bit 4).
__device__ __forceinline__ i32x8 read_frag(const uchar_t* arr, int off) {
    int4 lo = *reinterpret_cast<const int4*>(arr + off);
    int4 hi = *reinterpret_cast<const int4*>(arr + (off ^ 16));
    i32x8 r;
    r[0] = lo.x; r[1] = lo.y; r[2] = lo.z; r[3] = lo.w;
    r[4] = hi.x; r[5] = hi.y; r[6] = hi.z; r[7] = hi.w;
    return r;
}

// ---------------- fused fp8 GEMM (MX, unit scales) + CE ---------------------
// 256x128 block tile, 8 waves (4M x 2N), 64x64 per wave, acc[4][4] = 64 VGPR.
//
// Register-level one-tile-deep pipeline (round-2 post-mortem: frags read and
// consumed in the SAME phase serialized the LDS unit (8 waves x 16
// ds_read_b128 ~ 1900 cy incl. staging writes) against the MFMA wall
// (~1105 cy) -> tile makespan ~2400 cy, MfmaUtil 36%).  Now iteration t:
//     vmcnt(0)            -- STAGE(t+1), issued at iter t-1, has landed
//     s_barrier           -- all waves' staging visible; also fences buffer
//                            (t+2)%3: its frags were consumed by MFMAs(t-1),
//                            whose lgkm waits completed before this barrier
//     ds_read frags(t+1)  -- into the OTHER frag set (no consumer this iter)
//     STAGE(t+2)          -- 6 global_load_lds into buf (t+2)%3, in flight
//                            under this iter's MFMAs (~1100 cy > L2/L3 lat)
//     16 MFMA on frags(t) -- ZERO lgkm dependency; LDS unit streams t+1's
//                            reads concurrently
// All buffer/frag-set indices are compile-time (16 macro iterations) so no
// runtime-indexed register arrays (rule #20).  Two frag sets (128 VGPR) +
// acc (64) + addressing ~= 215 < 256; LDS 144 KiB caps at 1 block/CU anyway.
//
// LDS swizzle: physical 16B slot p of row r holds logical slot p ^ (r&7).
// Write side stays linear for global_load_lds (wave-uniform base + lane*16);
// each lane pre-swizzles its GLOBAL source slot (same involution).
__global__ __launch_bounds__(512, 2) void gemm_ce(
    const uchar_t* __restrict__ A,
    const uchar_t* __restrict__ B,
    const int* __restrict__ targets,
    float* __restrict__ sumexp,
    float* __restrict__ tgtlogit) {
    __shared__ alignas(16) uchar_t As[3][BM * BK];   // 3 x 32 KiB
    __shared__ alignas(16) uchar_t Bs[3][BN * BK];   // 3 x 16 KiB

    const int tid  = threadIdx.x;
    const int wave = tid >> 6;
    const int lane = tid & 63;
    const int quad = lane >> 4;
    const int l16  = lane & 15;
    const int wm   = (wave >> 1) * 64;   // wave grid: 4M x 2N, 64x64 each
    const int wn   = (wave & 1) * 64;

    const int m0 = blockIdx.x * BM;
    const int n0 = blockIdx.y * BN;

    // staging: per global_load_lds a wave writes 1024 B = 8 rows x 128 B,
    // linear in LDS. Wave w stages A rows [w*32, w*32+32) (4 loads) and
    // B rows [w*16, w*16+16) (2 loads). Lane L fetches global 16B slot
    // (L&7) ^ (row&7) so the linear LDS write lands the swizzled layout.
    const int srow = lane >> 3;
    const int sswz = ((lane & 7) ^ srow) << 4;
    const uchar_t* Ag = A + (size_t)(m0 + wave * 32 + srow) * DDIM + sswz;
    const uchar_t* Bg = B + (size_t)(n0 + wave * 16 + srow) * DDIM + sswz;

    // fragment read offsets: row = (wm|wn) + f*16 + l16, row&7 == l16&7
    const int swlo = ((quad << 1) ^ (l16 & 7)) << 4;
    const int aoff = (wm + l16) * BK + swlo;
    const int boff = (wn + l16) * BK + swlo;

    f32x4 acc[4][4];
    const f32x4 zero = {0.f, 0.f, 0.f, 0.f};
#pragma unroll
    for (int i = 0; i < 4; ++i)
#pragma unroll
        for (int j = 0; j < 4; ++j) acc[i][j] = zero;

    i32x8 af[2][4], bf[2][4];   // two frag sets, always statically indexed

#define STAGE(buf, kk)                                                         \
    do {                                                                       \
        uchar_t* a_ = &As[buf][0] + (wave * 32) * BK;                          \
        uchar_t* b_ = &Bs[buf][0] + (wave * 16) * BK;                          \
        _Pragma("unroll") for (int it_ = 0; it_ < 4; ++it_)                    \
            load_lds16(Ag + (size_t)it_ * 8 * DDIM + (kk), a_ + it_ * 8 * BK); \
        _Pragma("unroll") for (int it_ = 0; it_ < 2; ++it_)                    \
            load_lds16(Bg + (size_t)it_ * 8 * DDIM + (kk), b_ + it_ * 8 * BK); \
    } while (0)

#define READF(SET, buf)                                                        \
    do {                                                                       \
        _Pragma("unroll") for (int i_ = 0; i_ < 4; ++i_)                       \
            af[SET][i_] = read_frag(&As[buf][0], aoff + i_ * 16 * BK);         \
        _Pragma("unroll") for (int j_ = 0; j_ < 4; ++j_)                       \
            bf[SET][j_] = read_frag(&Bs[buf][0], boff + j_ * 16 * BK);         \
    } while (0)

#define MFMA16(SET)                                                            \
    do {                                                                       \
        __builtin_amdgcn_s_setprio(1);                                         \
        _Pragma("unroll") for (int i_ = 0; i_ < 4; ++i_)                       \
            _Pragma("unroll") for (int j_ = 0; j_ < 4; ++j_)                   \
                acc[i_][j_] = __builtin_amdgcn_mfma_scale_f32_16x16x128_f8f6f4(\
                    af[SET][i_], bf[SET][j_], acc[i_][j_],                     \
                    0, 0, 0, SCALE_ONE, 0, SCALE_ONE);                         \
        __builtin_amdgcn_s_setprio(0);                                         \
    } while (0)

#define VMCNT(n) asm volatile("s_waitcnt vmcnt(" #n ")" ::: "memory")
#define BARRIER  asm volatile("s_barrier" ::: "memory")

    // prologue: stage tiles 0,1; pre-read frags(0)
    STAGE(0, 0);
    STAGE(1, BK);
    VMCNT(6);          // STAGE(0) landed; STAGE(1) may still be in flight
    BARRIER;
    READF(0, 0);

    // iteration T: CUR=T%2, NXT=(T+1)%2, read buf (T+1)%3, stage buf (T+2)%3
#define ITER(T, CUR, NXT, BRD, BST, DO_STAGE)                                  \
    do {                                                                       \
        VMCNT(0);                                                              \
        BARRIER;                                                               \
        READF(NXT, BRD);                                                       \
        if (DO_STAGE) STAGE(BST, (T + 2) * BK);                                \
        MFMA16(CUR);                                                           \
    } while (0)

    ITER(0,  0, 1, 1, 2, 1);
    ITER(1,  1, 0, 2, 0, 1);
    ITER(2,  0, 1, 0, 1, 1);
    ITER(3,  1, 0, 1, 2, 1);
    ITER(4,  0, 1, 2, 0, 1);
    ITER(5,  1, 0, 0, 1, 1);
    ITER(6,  0, 1, 1, 2, 1);
    ITER(7,  1, 0, 2, 0, 1);
    ITER(8,  0, 1, 0, 1, 1);
    ITER(9,  1, 0, 1, 2, 1);
    ITER(10, 0, 1, 2, 0, 1);
    ITER(11, 1, 0, 0, 1, 1);
    ITER(12, 0, 1, 1, 2, 1);
    ITER(13, 1, 0, 2, 0, 1);
    ITER(14, 0, 1, 0, 1, 0);   // no tile 16 to stage
    MFMA16(1);                 // iteration 15: compute only

    // ---- epilogue: CE. C/D layout: row = quad*4 + reg, col = l16. ----
    // Pre-reduce the 2 N-waves' partial exp-sums in LDS -> 2x fewer global
    // atomics. LDS is dead after the sync.
    __syncthreads();
    float* sred = reinterpret_cast<float*>(&As[0][0]);   // [2][256] floats
#pragma unroll
    for (int i = 0; i < 4; ++i) {
#pragma unroll
        for (int r = 0; r < 4; ++r) {
            const int rloc = wm + i * 16 + quad * 4 + r;   // 0..255 in tile
            const int mg = m0 + rloc;
            const int t  = targets[mg];
            float p = 0.f;
#pragma unroll
            for (int j = 0; j < 4; ++j) {
                float v = acc[i][j][r] * INVSCALE;
                p += __expf(v);
                if (t == n0 + wn + j * 16 + l16) tgtlogit[mg] = v;
            }
            p += __shfl_xor(p, 1);
            p += __shfl_xor(p, 2);
            p += __shfl_xor(p, 4);
            p += __shfl_xor(p, 8);
            if (l16 == 0) sred[(wave & 1) * 256 + rloc] = p;
        }
    }
    __syncthreads();
    if (tid < 256) {
        float s = sred[tid] + sred[256 + tid];
        atomicAdd(&sumexp[m0 + tid], s);
    }

#undef STAGE
#undef READF
#undef MFMA16
#undef VMCNT
#undef BARRIER
#undef ITER
}

// ---------------- final reduction: loss = sum(log(sumexp)-tgt)/n_valid ------
__global__ void finalize(const float* __restrict__ sumexp,
                         const float* __restrict__ tgtlogit,
                         const int* __restrict__ targets,
                         float* __restrict__ out) {
    __shared__ float s_sum[16];
    __shared__ float s_cnt[16];
    float local = 0.f, cnt = 0.f;
    for (int t = threadIdx.x; t < MTOK; t += blockDim.x) {
        int tg = targets[t];
        if (tg != IGNORE_INDEX) {
            local += logf(sumexp[t]) - tgtlogit[t];
            cnt += 1.f;
        }
    }
#pragma unroll
    for (int o = 32; o > 0; o >>= 1) {
        local += __shfl_down(local, o);
        cnt   += __shfl_down(cnt, o);
    }
    const int wave = threadIdx.x >> 6, lane = threadIdx.x & 63;
    if (lane == 0) { s_sum[wave] = local; s_cnt[wave] = cnt; }
    __syncthreads();
    if (threadIdx.x == 0) {
        float ts = 0.f, tc = 0.f;
        for (int w = 0; w < (int)(blockDim.x >> 6); ++w) {
            ts += s_sum[w];
            tc += s_cnt[w];
        }
        out[0] = (tc > 0.f) ? (ts / tc) : ts;
    }
}

extern "C" void kernel_launch(void* const* d_in, const int* in_sizes, int n_in,
                              void* d_out, int out_size, void* d_ws,
                              size_t ws_size, hipStream_t stream) {
    const float* weight  = (const float*)d_in[0];   // [VOCAB][DDIM] fp32
    const float* hidden  = (const float*)d_in[1];   // [MTOK][DDIM] fp32
    const int*   targets = (const int*)d_in[2];     // [MTOK]
    float* out = (float*)d_out;

    const size_t wbytes = (size_t)VOCAB * DDIM;     // 65,536,000 (fp8)
    const size_t hbytes = (size_t)MTOK * DDIM;      // 16,777,216 (fp8)
    uchar_t* Wb = (uchar_t*)d_ws;
    uchar_t* Hb = (uchar_t*)d_ws + wbytes;
    float* sumexp   = (float*)((char*)d_ws + wbytes + hbytes);
    float* tgtlogit = sumexp + MTOK;

    // fp32 -> fp8 conversion for both tensors + zero accumulators, one launch
    cvt_f32_fp8<<<WBLK + HBLK + ZBLK, 256, 0, stream>>>(
        (const float4*)weight, (int4*)Wb, (const float4*)hidden, (int4*)Hb,
        (int4*)sumexp);

    dim3 grid(MTOK / BM, VOCAB / BN);   // 32 x 250
    gemm_ce<<<grid, 512, 0, stream>>>(Hb, Wb, targets, sumexp, tgtlogit);

    finalize<<<1, 1024, 0, stream>>>(sumexp, tgtlogit, targets, out);
}

// Round 4
// 934.852 us; speedup vs baseline: 7.6494x; 7.6494x over previous
//
#include <hip/hip_runtime.h>

#define IGNORE_INDEX (-100)
#define VOCAB 32000
#define DDIM  2048      /* K in elements; == bytes per row in fp8 */
#define MTOK  8192      /* B*S = 4*2048 */

#define BM 256
#define BN 256
#define BK 128          /* fp8 elems (bytes) per K-tile */
#define NKT (DDIM / BK) /* 16 K-tiles */

#define WSCALE 32.0f
#define HSCALE 8.0f
#define INVSCALE (1.0f / 256.0f)
#define SCALE_ONE 0x7F7F7F7F  /* e8m0 1.0 in every byte */

#define WBLK ((VOCAB * DDIM) / (256 * 16))   /* 16000 */
#define HBLK ((MTOK * DDIM) / (256 * 16))    /*  4096 */
#define ZBLK ((2 * MTOK * 4) / (256 * 16))   /*    16: zero sumexp+tgtlogit */

typedef float f32x4 __attribute__((ext_vector_type(4)));
typedef int   i32x8 __attribute__((ext_vector_type(8)));
typedef unsigned char uchar_t;

// ---------------- fp32 -> fp8 e4m3 (OCP, RNE via HW cvt), 16 elems/thread ----
__device__ __forceinline__ void cvt16(const float4* __restrict__ src,
                                      int4* __restrict__ dst, float scale,
                                      size_t i) {
    float4 a = src[4 * i], b = src[4 * i + 1], c = src[4 * i + 2], d = src[4 * i + 3];
    int4 o;
    int v;
    v = 0;
    v = __builtin_amdgcn_cvt_pk_fp8_f32(a.x * scale, a.y * scale, v, false);
    v = __builtin_amdgcn_cvt_pk_fp8_f32(a.z * scale, a.w * scale, v, true);
    o.x = v;
    v = 0;
    v = __builtin_amdgcn_cvt_pk_fp8_f32(b.x * scale, b.y * scale, v, false);
    v = __builtin_amdgcn_cvt_pk_fp8_f32(b.z * scale, b.w * scale, v, true);
    o.y = v;
    v = 0;
    v = __builtin_amdgcn_cvt_pk_fp8_f32(c.x * scale, c.y * scale, v, false);
    v = __builtin_amdgcn_cvt_pk_fp8_f32(c.z * scale, c.w * scale, v, true);
    o.z = v;
    v = 0;
    v = __builtin_amdgcn_cvt_pk_fp8_f32(d.x * scale, d.y * scale, v, false);
    v = __builtin_amdgcn_cvt_pk_fp8_f32(d.z * scale, d.w * scale, v, true);
    o.w = v;
    dst[i] = o;
}

// Fused: weight cvt | hidden cvt | zero accumulators (ws poisoned each call).
__global__ void cvt_f32_fp8(const float4* __restrict__ srcW, int4* __restrict__ dstW,
                            const float4* __restrict__ srcH, int4* __restrict__ dstH,
                            int4* __restrict__ zr) {
    if (blockIdx.x < WBLK) {
        size_t i = (size_t)blockIdx.x * blockDim.x + threadIdx.x;
        cvt16(srcW, dstW, WSCALE, i);
    } else if (blockIdx.x < WBLK + HBLK) {
        size_t i = (size_t)(blockIdx.x - WBLK) * blockDim.x + threadIdx.x;
        cvt16(srcH, dstH, HSCALE, i);
    } else {
        int i = (blockIdx.x - WBLK - HBLK) * 256 + threadIdx.x;
        zr[i] = make_int4(0, 0, 0, 0);
    }
}

// ---------------- async global -> LDS (16 B per lane) ----------------
__device__ __forceinline__ void load_lds16(const uchar_t* g, uchar_t* l) {
    __builtin_amdgcn_global_load_lds(
        (const __attribute__((address_space(1))) unsigned int*)(const void*)g,
        (__attribute__((address_space(3))) unsigned int*)(void*)l,
        16, 0, 0);
}

// 32 B fragment read with 16B-slot XOR swizzle: logical slots (2q, 2q+1) of a
// row live at physical slots (2q)^(row&7), (2q+1)^(row&7). off already encodes
// row*BK + ((2q)^(row&7))<<4; the odd slot is off^16 (XOR flips only bit 4).
__device__ __forceinline__ i32x8 read_frag(const uchar_t* arr, int off) {
    int4 lo = *reinterpret_cast<const int4*>(arr + off);
    int4 hi = *reinterpret_cast<const int4*>(arr + (off ^ 16));
    i32x8 r;
    r[0] = lo.x; r[1] = lo.y; r[2] = lo.z; r[3] = lo.w;
    r[4] = hi.x; r[5] = hi.y; r[6] = hi.z; r[7] = hi.w;
    return r;
}

// ---------------- fused fp8 GEMM (MX, unit scales) + CE ---------------------
// 256x256 block tile, 8 waves (2M x 4N), 128x64 per wave.
//
// Why 256x256 (round-2 post-mortem): at 256x128 the LDS unit serves ~1912
// cy/tile (8 waves x 16 ds_read_b128 + staging writes) against an 1100-cy
// MFMA wall -> MfmaUtil ceiling 57%, measured 36%. At 256x256 the per-wave
// frag count drops to 12 (A 8 + B 4) while FLOPs double: LDS ~2816 cy vs
// MFMA 2200 cy -> ceiling ~78%.
//
// Register discipline (rounds 1/3 post-mortem): gfx950 unified file splits
// at accum_offset; acc lives on the AGPR side (acc[8][4] = 128), and the
// ARCH side must hold frags+addressing within ~128.  Frags are read AND
// consumed inside one phase, M-split into two halves:
//   read bf[0..3], afA[0..3] -> 16 MFMA -> read afB[0..3] -> 16 MFMA
// so peak arch liveness ~= 32+32+32+addr < 128.  Nothing but acc crosses a
// barrier.
//
// Double-buffered LDS (2 x 64 KiB), one barrier per K-tile (round-2 proven):
//   iter t: { vmcnt(0)  -- own staging of tile t (issued at t-1) landed
//             s_barrier -- everyone's tile-t staged; also fences buf (t+1)&1
//                          whose frags were consumed before this barrier
//             ds_read frags of tile t ; STAGE(t+1) into buf (t+1)&1 ;
//             32 MFMA }
//   Staging has the whole ~2800-cy compute phase to land (>> L2 latency).
//
// LDS swizzle: physical 16B slot p of row r holds logical slot p ^ (r&7).
// Write side stays linear for global_load_lds (wave-uniform base + lane*16);
// each lane pre-swizzles its GLOBAL source slot (same involution).
__global__ __launch_bounds__(512, 2) void gemm_ce(
    const uchar_t* __restrict__ A,
    const uchar_t* __restrict__ B,
    const int* __restrict__ targets,
    float* __restrict__ sumexp,
    float* __restrict__ tgtlogit) {
    __shared__ alignas(16) uchar_t As[2][BM * BK];   // 2 x 32 KiB
    __shared__ alignas(16) uchar_t Bs[2][BN * BK];   // 2 x 32 KiB

    const int tid  = threadIdx.x;
    const int wave = tid >> 6;
    const int lane = tid & 63;
    const int quad = lane >> 4;
    const int l16  = lane & 15;
    const int wm   = (wave >> 2) * 128;  // wave grid: 2M x 4N, 128x64 each
    const int wn   = (wave & 3) * 64;

    const int m0 = blockIdx.x * BM;
    const int n0 = blockIdx.y * BN;

    // staging: per global_load_lds a wave writes 1024 B = 8 rows x 128 B,
    // linear in LDS. Wave w stages A rows [w*32, w*32+32) (4 loads) and
    // B rows [w*32, w*32+32) (4 loads). Lane L fetches global 16B slot
    // (L&7) ^ (row&7) so the linear LDS write lands the swizzled layout.
    const int srow = lane >> 3;
    const int sswz = ((lane & 7) ^ srow) << 4;
    const uchar_t* Ag = A + (size_t)(m0 + wave * 32 + srow) * DDIM + sswz;
    const uchar_t* Bg = B + (size_t)(n0 + wave * 32 + srow) * DDIM + sswz;

    // fragment read offsets: row = (wm|wn) + f*16 + l16, row&7 == l16&7
    const int swlo = ((quad << 1) ^ (l16 & 7)) << 4;
    const int aoff = (wm + l16) * BK + swlo;
    const int boff = (wn + l16) * BK + swlo;

    f32x4 acc[8][4];
    const f32x4 zero = {0.f, 0.f, 0.f, 0.f};
#pragma unroll
    for (int i = 0; i < 8; ++i)
#pragma unroll
        for (int j = 0; j < 4; ++j) acc[i][j] = zero;

#define STAGE(buf, kk)                                                         \
    do {                                                                       \
        uchar_t* a_ = &As[buf][0] + (wave * 32) * BK;                          \
        uchar_t* b_ = &Bs[buf][0] + (wave * 32) * BK;                          \
        _Pragma("unroll") for (int it_ = 0; it_ < 4; ++it_)                    \
            load_lds16(Ag + (size_t)it_ * 8 * DDIM + (kk), a_ + it_ * 8 * BK); \
        _Pragma("unroll") for (int it_ = 0; it_ < 4; ++it_)                    \
            load_lds16(Bg + (size_t)it_ * 8 * DDIM + (kk), b_ + it_ * 8 * BK); \
    } while (0)

// one K-tile: read frags in-phase (M-split halves), PREFETCH between the
// ds_reads and the MFMAs (round-2 proven order).
#define COMPUTE(buf)                                                           \
    do {                                                                       \
        const uchar_t* as_ = &As[buf][0];                                      \
        const uchar_t* bs_ = &Bs[buf][0];                                      \
        i32x8 bfr[4], afA[4];                                                  \
        _Pragma("unroll") for (int j_ = 0; j_ < 4; ++j_)                       \
            bfr[j_] = read_frag(bs_, boff + j_ * 16 * BK);                     \
        _Pragma("unroll") for (int i_ = 0; i_ < 4; ++i_)                       \
            afA[i_] = read_frag(as_, aoff + i_ * 16 * BK);                     \
        PREFETCH;                                                              \
        __builtin_amdgcn_s_setprio(1);                                         \
        _Pragma("unroll") for (int i_ = 0; i_ < 4; ++i_)                       \
            _Pragma("unroll") for (int j_ = 0; j_ < 4; ++j_)                   \
                acc[i_][j_] = __builtin_amdgcn_mfma_scale_f32_16x16x128_f8f6f4(\
                    afA[i_], bfr[j_], acc[i_][j_],                             \
                    0, 0, 0, SCALE_ONE, 0, SCALE_ONE);                         \
        __builtin_amdgcn_s_setprio(0);                                         \
        i32x8 afB[4];                                                          \
        _Pragma("unroll") for (int i_ = 0; i_ < 4; ++i_)                       \
            afB[i_] = read_frag(as_, aoff + (i_ + 4) * 16 * BK);               \
        __builtin_amdgcn_s_setprio(1);                                         \
        _Pragma("unroll") for (int i_ = 0; i_ < 4; ++i_)                       \
            _Pragma("unroll") for (int j_ = 0; j_ < 4; ++j_)                   \
                acc[i_ + 4][j_] = __builtin_amdgcn_mfma_scale_f32_16x16x128_f8f6f4(\
                    afB[i_], bfr[j_], acc[i_ + 4][j_],                         \
                    0, 0, 0, SCALE_ONE, 0, SCALE_ONE);                         \
        __builtin_amdgcn_s_setprio(0);                                         \
    } while (0)

#define VMCNT0  asm volatile("s_waitcnt vmcnt(0)" ::: "memory")
#define BARRIER asm volatile("s_barrier" ::: "memory")

    // prologue: stage K-tile 0 into buffer 0
    STAGE(0, 0);
    VMCNT0;
    BARRIER;

#pragma clang loop unroll(disable)
    for (int t = 0; t < NKT - 1; ++t) {
        const int cur = t & 1;
#define PREFETCH STAGE(cur ^ 1, (t + 1) * BK)
        COMPUTE(cur);
#undef PREFETCH
        VMCNT0;    // tile t+1 staging landed
        BARRIER;   // everyone done reading buf cur; buf cur^1 fully staged
    }
#define PREFETCH
    COMPUTE(1);    // tile 15 (NKT-1 is odd -> buffer 1)
#undef PREFETCH

    // ---- epilogue: CE. C/D layout: row = quad*4 + reg, col = l16. ----
    // Pre-reduce the 4 N-waves' partial exp-sums in LDS -> 4x fewer global
    // atomics. LDS is dead after the sync.
    __syncthreads();
    float* sred = reinterpret_cast<float*>(&As[0][0]);   // [4][256] floats
#pragma unroll
    for (int i = 0; i < 8; ++i) {
#pragma unroll
        for (int r = 0; r < 4; ++r) {
            const int rloc = wm + i * 16 + quad * 4 + r;   // 0..255 in tile
            const int mg = m0 + rloc;
            const int t  = targets[mg];
            float p = 0.f;
#pragma unroll
            for (int j = 0; j < 4; ++j) {
                float v = acc[i][j][r] * INVSCALE;
                p += __expf(v);
                if (t == n0 + wn + j * 16 + l16) tgtlogit[mg] = v;
            }
            p += __shfl_xor(p, 1);
            p += __shfl_xor(p, 2);
            p += __shfl_xor(p, 4);
            p += __shfl_xor(p, 8);
            if (l16 == 0) sred[(wave & 3) * 256 + rloc] = p;
        }
    }
    __syncthreads();
    if (tid < 256) {
        float s = sred[tid] + sred[256 + tid] + sred[512 + tid] + sred[768 + tid];
        atomicAdd(&sumexp[m0 + tid], s);
    }

#undef STAGE
#undef COMPUTE
#undef VMCNT0
#undef BARRIER
}

// ---------------- final reduction: loss = sum(log(sumexp)-tgt)/n_valid ------
__global__ void finalize(const float* __restrict__ sumexp,
                         const float* __restrict__ tgtlogit,
                         const int* __restrict__ targets,
                         float* __restrict__ out) {
    __shared__ float s_sum[16];
    __shared__ float s_cnt[16];
    float local = 0.f, cnt = 0.f;
    for (int t = threadIdx.x; t < MTOK; t += blockDim.x) {
        int tg = targets[t];
        if (tg != IGNORE_INDEX) {
            local += logf(sumexp[t]) - tgtlogit[t];
            cnt += 1.f;
        }
    }
#pragma unroll
    for (int o = 32; o > 0; o >>= 1) {
        local += __shfl_down(local, o);
        cnt   += __shfl_down(cnt, o);
    }
    const int wave = threadIdx.x >> 6, lane = threadIdx.x & 63;
    if (lane == 0) { s_sum[wave] = local; s_cnt[wave] = cnt; }
    __syncthreads();
    if (threadIdx.x == 0) {
        float ts = 0.f, tc = 0.f;
        for (int w = 0; w < (int)(blockDim.x >> 6); ++w) {
            ts += s_sum[w];
            tc += s_cnt[w];
        }
        out[0] = (tc > 0.f) ? (ts / tc) : ts;
    }
}

extern "C" void kernel_launch(void* const* d_in, const int* in_sizes, int n_in,
                              void* d_out, int out_size, void* d_ws,
                              size_t ws_size, hipStream_t stream) {
    const float* weight  = (const float*)d_in[0];   // [VOCAB][DDIM] fp32
    const float* hidden  = (const float*)d_in[1];   // [MTOK][DDIM] fp32
    const int*   targets = (const int*)d_in[2];     // [MTOK]
    float* out = (float*)d_out;

    const size_t wbytes = (size_t)VOCAB * DDIM;     // 65,536,000 (fp8)
    const size_t hbytes = (size_t)MTOK * DDIM;      // 16,777,216 (fp8)
    uchar_t* Wb = (uchar_t*)d_ws;
    uchar_t* Hb = (uchar_t*)d_ws + wbytes;
    float* sumexp   = (float*)((char*)d_ws + wbytes + hbytes);
    float* tgtlogit = sumexp + MTOK;

    // fp32 -> fp8 conversion for both tensors + zero accumulators, one launch
    cvt_f32_fp8<<<WBLK + HBLK + ZBLK, 256, 0, stream>>>(
        (const float4*)weight, (int4*)Wb, (const float4*)hidden, (int4*)Hb,
        (int4*)sumexp);

    dim3 grid(MTOK / BM, VOCAB / BN);   // 32 x 125
    gemm_ce<<<grid, 512, 0, stream>>>(Hb, Wb, targets, sumexp, tgtlogit);

    finalize<<<1, 1024, 0, stream>>>(sumexp, tgtlogit, targets, out);
}